// Round 5
// baseline (69.698 us; speedup 1.0000x reference)
//
#include <hip/hip_runtime.h>
#include <hip/hip_bf16.h>

// Problem constants (from reference)
#define UNITS 512
#define CONN  512
#define SEQL  32

typedef __hip_bfloat16 bf16;
typedef __attribute__((ext_vector_type(8))) short short8;   // 8 bf16 = MFMA A/B frag
typedef __attribute__((ext_vector_type(4))) float floatx4;  // MFMA C/D frag

// out[b,u] = relu( sum_c x[b,c] * kernel[u] * dendriticW[dendrites[u,c], u] + bias[u] )
// == 512^3 GEMM with gather-built weights. Inputs/outputs are fp32 (verified
// rounds 1-4); we quantize x and W to bf16 for MFMA (absmax ~2e-3 vs 9.8e-3
// threshold, measured round 4).
//
// Single fused kernel, no d_ws:
//   * 256 blocks (1/CU), each = 16 units x 64 batches.
//   * Build: gather W[16][512] into LDS in MFMA B-frag order (wl[kb][lane]),
//     4 x ds_write_b128 per thread, conflict-spread via 65-short8 row stride.
//   * Compute: 4 waves x one 16x16 tile, K=512 unrolled: 16 x (2 float4 x-load
//     + cvt + ds_read_b128 + mfma_f32_16x16x32_bf16). No W global round-trip,
//     no prep->gemm serialization, one launch.
// Frag layouts (learn_hip m89/m92-verified):
//   A[m=lane&15][k=(lane>>4)*8+j]; B idem from B^T rows; C/D col=lane&15,
//   row=(lane>>4)*4+reg.

union cv8 { bf16 h[8]; short8 v; };

__global__ __launch_bounds__(256) void dendriter_fused_mfma(
    const float* __restrict__ x,     // [batch*CONN] fp32
    const float* __restrict__ kern,  // [UNITS] fp32
    const float* __restrict__ dW,    // [SEQL*UNITS] fp32
    const float* __restrict__ bias,  // [UNITS] fp32
    const int*   __restrict__ dend,  // [UNITS*CONN] int32
    float* __restrict__ out)         // [batch*UNITS] fp32
{
    // wl[kb][lane_id]: 16B B-frag for k-block kb, MFMA lane lane_id.
    // 65 (not 64) short8 per row: bank-start = 4*(kb+lane) % 32 -> even spread.
    __shared__ short8 wl[16][65];

    const int t  = threadIdx.x;          // 0..255
    const int ut = blockIdx.x * 16;      // unit tile (32 tiles)
    const int bt = blockIdx.y * 64;      // batch tile (8 tiles)

    // ---------------- build phase: W tile -> LDS (B-frag order) ----------------
    {
        const int ul  = t >> 4;          // unit_local 0..15
        const int cg0 = (t & 15) * 4;    // first of 4 groups of 8 conns
        const int u   = ut + ul;
        const float kv = kern[u];
        // 32 consecutive dend entries: 128B aligned, coalesced across threads
        const int4* dp = (const int4*)(dend + u * CONN + cg0 * 8);
#pragma unroll
        for (int j = 0; j < 4; ++j) {
            const int4 s0 = dp[2 * j];
            const int4 s1 = dp[2 * j + 1];
            const int segs[8] = {s0.x, s0.y, s0.z, s0.w, s1.x, s1.y, s1.z, s1.w};
            cv8 w;
#pragma unroll
            for (int i = 0; i < 8; ++i)   // dW: 64 KB table, L1/L2-resident
                w.h[i] = __float2bfloat16(kv * dW[segs[i] * UNITS + u]);
            const int cg = cg0 + j;       // group -> (kb, q): c0 = cg*8
            const int kb = cg >> 2;
            const int q  = cg & 3;
            wl[kb][ul | (q << 4)] = w.v;  // frag element i <-> c = kb*32+q*8+i
        }
    }
    __syncthreads();

    // ---------------- compute phase: 1 wave per 16x16 out tile ----------------
    const int lane = t & 63;
    const int wv   = t >> 6;             // 0..3 -> batch sub-tile
    const int m = lane & 15;
    const int q = lane >> 4;
    const int btw = bt + wv * 16;

    const float* xrow = x + (size_t)(btw + m) * CONN + q * 8;
    floatx4 acc = {0.f, 0.f, 0.f, 0.f};
#pragma unroll
    for (int kb = 0; kb < 16; ++kb) {
        const float4 f0 = *(const float4*)(xrow + kb * 32);
        const float4 f1 = *(const float4*)(xrow + kb * 32 + 4);
        cv8 a;
        a.h[0] = __float2bfloat16(f0.x); a.h[1] = __float2bfloat16(f0.y);
        a.h[2] = __float2bfloat16(f0.z); a.h[3] = __float2bfloat16(f0.w);
        a.h[4] = __float2bfloat16(f1.x); a.h[5] = __float2bfloat16(f1.y);
        a.h[6] = __float2bfloat16(f1.z); a.h[7] = __float2bfloat16(f1.w);
        const short8 b = wl[kb][lane];   // contiguous lane*16B: conflict-free
        acc = __builtin_amdgcn_mfma_f32_16x16x32_bf16(a.v, b, acc, 0, 0, 0);
    }

    const float bu = bias[ut + m];
#pragma unroll
    for (int r = 0; r < 4; ++r) {
        float v = acc[r] + bu;
        v = v > 0.f ? v : 0.f;
        out[(size_t)(btw + q * 4 + r) * UNITS + ut + m] = v;
    }
}

extern "C" void kernel_launch(void* const* d_in, const int* in_sizes, int n_in,
                              void* d_out, int out_size, void* d_ws, size_t ws_size,
                              hipStream_t stream) {
    // setup_inputs() order: x, kernel, dendriticW, bias, dendrites — all fp32
    const float* x    = (const float*)d_in[0];
    const float* kern = (const float*)d_in[1];
    const float* dW   = (const float*)d_in[2];
    const float* bias = (const float*)d_in[3];
    const int*   dend = (const int*)  d_in[4];
    float* out = (float*)d_out;

    const int batch = in_sizes[0] / CONN;   // 512
    dendriter_fused_mfma<<<dim3(UNITS / 16, batch / 64), 256, 0, stream>>>(
        x, kern, dW, bias, dend, out);
}